// Round 14
// baseline (454.553 us; speedup 1.0000x reference)
//
#include <hip/hip_runtime.h>
#include <math.h>

#define N_NODES   50000
#define N_EDGES   400000
#define N_GRAPHS  500
#define CAND_MAX  262144
#define DELTA     8e-3f
#define CAP       64

typedef __attribute__((ext_vector_type(8))) _Float16 f16x8;
typedef __attribute__((ext_vector_type(4))) float f32x4;

// ---------- helpers ----------
__device__ __forceinline__ float elu_f(float v) { return v > 0.f ? v : expm1f(v); }   // exact-refine grade
__device__ __forceinline__ float elu_fast(float v) {
    return fmaxf(v, 0.f) + (__expf(fminf(v, 0.f)) - 1.f);
}
__device__ __forceinline__ unsigned enc_f(float f) {
    unsigned u = __float_as_uint(f);
    return (u & 0x80000000u) ? ~u : (u | 0x80000000u);
}
__device__ __forceinline__ float dec_f(unsigned u) {
    return __uint_as_float((u & 0x80000000u) ? (u & 0x7FFFFFFFu) : ~u);
}
__device__ __forceinline__ unsigned short f2h_bits(float f) {
    _Float16 h = (_Float16)f;
    return __builtin_bit_cast(unsigned short, h);
}
__device__ __forceinline__ float h2f(unsigned short b) {
    return (float)__builtin_bit_cast(_Float16, b);
}

// ---------- 1) bucket placement + meta + weight prep + f32 transpose (fused) ----------
__global__ void k_place(const int* __restrict__ src, const int* __restrict__ dst,
                        const unsigned char* __restrict__ state, const int* __restrict__ batch,
                        unsigned* __restrict__ cnt, unsigned* __restrict__ bucket,
                        unsigned short* __restrict__ meta,
                        const float* __restrict__ W1, const float* __restrict__ W2,
                        const float* __restrict__ W3, const float* __restrict__ P1,
                        const float* __restrict__ P2, char* __restrict__ Bpp,
                        float* __restrict__ Wt)
{
    if (blockIdx.x < 1563) {
        int e = blockIdx.x * 256 + threadIdx.x;
        if (e >= N_EDGES) return;
        int d = dst[e];
        int s = src[e];
        unsigned char st = state[e];
        unsigned idx = atomicAdd(&cnt[d], 1u);
        if (idx < CAP) bucket[d * CAP + idx] = (unsigned)s | (st ? 0x80000000u : 0u);
        int g = batch[s];
        meta[e] = (unsigned short)(g | (st ? 0 : 0x8000));
        return;
    }
    if (blockIdx.x >= 1624) {
        // ---- f32 transposed weights for the exact-refine arbiter ----
        int t2 = (blockIdx.x - 1624) * 256 + threadIdx.x;   // 0..61439
        if (t2 < 16384)      Wt[t2]         = W1[(t2 % 64) * 256 + t2 / 64];                 // W1t [256][64]
        else if (t2 < 49152) { int t = t2 - 16384; Wt[t2] = W2[(t % 256) * 128 + t / 256]; } // W2t [128][256]
        else if (t2 < 57344) { int t = t2 - 49152; Wt[t2] = W3[(t % 128) * 64 + t / 128]; }  // W3t [64][128]
        else                 { int t = t2 - 57344; Wt[t2] = P1[(t % 64) * 64 + t / 64]; }    // P1t [64][64]
        return;
    }
    // ---- weight prep: split f32 -> (Wh, Wl) f16, fragment-ordered (lo plane kept for layout compat) ----
    int tid = (blockIdx.x - 1563) * 256 + threadIdx.x;
    if (tid >= 15616) return;
    const float* W; int K, NT, Nreal, base, i;
    if (tid < 4096)       { W = W1; K = 64;  NT = 16; Nreal = 256; base = 0;      i = tid; }
    else if (tid < 12288) { W = W2; K = 256; NT = 8;  Nreal = 128; base = 65536;  i = tid - 4096; }
    else if (tid < 14336) { W = W3; K = 128; NT = 4;  Nreal = 64;  base = 196608; i = tid - 12288; }
    else if (tid < 15360) { W = P1; K = 64;  NT = 4;  Nreal = 64;  base = 229376; i = tid - 14336; }
    else                  { W = P2; K = 64;  NT = 1;  Nreal = 10;  base = 245760; i = tid - 15360; }
    int KB = K / 32;
    int lane = i & 63; int i2 = i >> 6;
    int nt = i2 % NT; int i3 = i2 / NT;
    int kb = i3 % KB; int ps = i3 / KB;
    unsigned short s[8];
    #pragma unroll
    for (int j = 0; j < 8; ++j) {
        int k = kb * 32 + ((lane >> 4) << 3) + j;
        int n = nt * 16 + (lane & 15);
        float wv = (n < Nreal) ? W[k * Nreal + n] : 0.f;
        unsigned short h = f2h_bits(wv);
        s[j] = ps ? f2h_bits(wv - h2f(h)) : h;
    }
    uint4 u;
    u.x = (unsigned)s[0] | ((unsigned)s[1] << 16);
    u.y = (unsigned)s[2] | ((unsigned)s[3] << 16);
    u.z = (unsigned)s[4] | ((unsigned)s[5] << 16);
    u.w = (unsigned)s[6] | ((unsigned)s[7] << 16);
    int frag = (ps * KB + kb) * NT + nt;
    *reinterpret_cast<uint4*>(Bpp + base + frag * 1024 + lane * 16) = u;
}

// ---------- 2) fused gather-aggregate + node reps (chunked gathers, same FP order) ----------
__global__ void k_aggrep(const float* __restrict__ x, const unsigned* __restrict__ cnt,
                         const unsigned* __restrict__ bucket, const float* __restrict__ Wg,
                         const float* __restrict__ bg, float* __restrict__ reps)
{
    __shared__ float sv[4][128];
    const int w = threadIdx.x >> 6, j = threadIdx.x & 63;
    const int n = blockIdx.x * 4 + w;
    unsigned c = cnt[n]; if (c > CAP) c = CAP;
    float sf = 0.f, so = 0.f;
    unsigned i = 0;
    for (; i + 4 <= c; i += 4) {
        unsigned p0 = bucket[n * CAP + i];
        unsigned p1 = bucket[n * CAP + i + 1];
        unsigned p2 = bucket[n * CAP + i + 2];
        unsigned p3 = bucket[n * CAP + i + 3];
        float v0 = x[(p0 & 0x7FFFFFFFu) * 64 + j];
        float v1 = x[(p1 & 0x7FFFFFFFu) * 64 + j];
        float v2 = x[(p2 & 0x7FFFFFFFu) * 64 + j];
        float v3 = x[(p3 & 0x7FFFFFFFu) * 64 + j];
        sf += v0; if (p0 & 0x80000000u) so += v0;
        sf += v1; if (p1 & 0x80000000u) so += v1;
        sf += v2; if (p2 & 0x80000000u) so += v2;
        sf += v3; if (p3 & 0x80000000u) so += v3;
    }
    for (; i < c; ++i) {
        unsigned p = bucket[n * CAP + i];
        float v = x[(p & 0x7FFFFFFFu) * 64 + j];
        sf += v;
        if (p & 0x80000000u) so += v;
    }
    float xv = x[n * 64 + j];
    sv[w][j]      = xv + sf;
    sv[w][64 + j] = xv + so;
    __syncthreads();
    const int o = j & 31;
    const float* svp = sv[w] + ((j >> 5) ? 64 : 0);
    float acc = 0.f;
    #pragma unroll 16
    for (int i2 = 0; i2 < 64; ++i2) acc += svp[i2] * Wg[i2 * 32 + o];
    float val = elu_fast(acc + bg[o]);
    float other = __shfl_xor(val, 32, 64);
    if (j < 32) reps[n * 32 + o] = val - other;
}

// ---------- 3) fused MFMA MLP: 64 edges/block, f16 hi-only acts, HI-ONLY weights ----------
// LDS rotation: region A 16 KB @0, region B 32 KB @16384 -> 48 KB -> 3 blocks/CU.
#define OFF_A 0
#define OFF_B 16384
#define SM_BYTES 49152

template<int K, int N, int ACT>   // ACT: 0 linear, 1 elu
__device__ __forceinline__ void run_layer(char* sm, const char* gB, int inOff, int outOff,
                                          const float* __restrict__ bias, int w, int lane)
{
    constexpr int KB  = K / 32;
    constexpr int NT  = N / 16;
    constexpr int NTC = (NT < 8) ? NT : 8;
    constexpr int NH  = NT / NTC;
    constexpr int NTW = (NTC >= 4) ? (NTC / 4) : 1;

    __syncthreads();

    const int row0 = lane & 15;
    const int hi16 = (lane >> 4) * 16;   // byte offset of k-subgroup

    #pragma unroll
    for (int nh = 0; nh < NH; ++nh) {
        f32x4 C[4][NTW];
        #pragma unroll
        for (int q = 0; q < NTW; ++q) {
            int nt = (w * NTW + q) % NTC;
            int n  = nh * NTC * 16 + nt * 16 + row0;
            float b = bias[n];
            #pragma unroll
            for (int mt = 0; mt < 4; ++mt) C[mt][q] = (f32x4){b, b, b, b};
        }

        #pragma unroll
        for (int kb = 0; kb < KB; ++kb) {
            f16x8 Ah[4];
            #pragma unroll
            for (int mt = 0; mt < 4; ++mt) {
                int row = mt * 16 + row0;
                int off = (((row * K + kb * 32) * 2) + hi16) ^ ((row & 7) << 4);
                Ah[mt] = *reinterpret_cast<const f16x8*>(sm + inOff + off);
            }
            #pragma unroll
            for (int q = 0; q < NTW; ++q) {
                int nt = (w * NTW + q) % NTC;
                const char* bp = gB + ((kb * NT + nh * NTC + nt) * 1024) + lane * 16;
                f16x8 Bh = *reinterpret_cast<const f16x8*>(bp);
                #pragma unroll
                for (int mt = 0; mt < 4; ++mt)
                    C[mt][q] = __builtin_amdgcn_mfma_f32_16x16x32_f16(Ah[mt], Bh, C[mt][q], 0, 0, 0);
            }
        }

        // epilogue (hi-only f16 store)
        #pragma unroll
        for (int q = 0; q < NTW; ++q) {
            int nt = (w * NTW + q) % NTC;
            int n  = nh * NTC * 16 + nt * 16 + row0;
            (void)n;
            #pragma unroll
            for (int mt = 0; mt < 4; ++mt) {
                #pragma unroll
                for (int r = 0; r < 4; ++r) {
                    int row = mt * 16 + (lane >> 4) * 4 + r;
                    float v = C[mt][q][r];
                    if (ACT == 1) v = elu_fast(v);
                    int off = ((row * N + n) * 2) ^ ((row & 7) << 4);
                    *reinterpret_cast<unsigned short*>(sm + outOff + off) = f2h_bits(v);
                }
            }
        }
    }
}

__global__ __launch_bounds__(256, 3) void k_mlp(
    const float* __restrict__ reps, const int* __restrict__ src, const int* __restrict__ dst,
    const unsigned short* __restrict__ meta, const int* __restrict__ y,
    const float* __restrict__ b1, const float* __restrict__ b2, const float* __restrict__ b3,
    const float* __restrict__ pb1, const float* __restrict__ pb2,
    const char* __restrict__ Bpp, float* __restrict__ lg_out, unsigned* __restrict__ m_u)
{
    __shared__ char sm[SM_BYTES];
    __shared__ int sSrc[64], sDst[64], sG[64], sCol[64], sAvail[64];
    const int t = threadIdx.x, w = t >> 6, lane = t & 63;
    const int ebase = blockIdx.x * 64;

    if (t < 64) {
        int e = ebase + t;
        sSrc[t] = src[e]; sDst[t] = dst[e];
        unsigned m = meta[e];
        int g = m & 0x1ff;
        sG[t] = g; sCol[t] = y[g];
        sAvail[t] = (m >> 15) & 1;
    }
    __syncthreads();

    // stage input tile: concat(reps[src], reps[dst]) -> f16, swizzled -> region A
    {
        int e = t >> 2, f0 = (t & 3) * 16;
        const float* rp = (f0 < 32) ? (reps + sSrc[e] * 32 + f0) : (reps + sDst[e] * 32 + (f0 - 32));
        float4 v0 = *reinterpret_cast<const float4*>(rp);
        float4 v1 = *reinterpret_cast<const float4*>(rp + 4);
        float4 v2 = *reinterpret_cast<const float4*>(rp + 8);
        float4 v3 = *reinterpret_cast<const float4*>(rp + 12);
        float vv[16] = {v0.x,v0.y,v0.z,v0.w, v1.x,v1.y,v1.z,v1.w,
                        v2.x,v2.y,v2.z,v2.w, v3.x,v3.y,v3.z,v3.w};
        unsigned pk[8];
        #pragma unroll
        for (int i = 0; i < 8; ++i)
            pk[i] = (unsigned)f2h_bits(vv[2*i]) | ((unsigned)f2h_bits(vv[2*i+1]) << 16);
        int b0 = (e * 64 + f0) * 2;
        uint4 u0 = {pk[0], pk[1], pk[2], pk[3]};
        uint4 u1 = {pk[4], pk[5], pk[6], pk[7]};
        *reinterpret_cast<uint4*>(sm + OFF_A + (b0 ^ ((e & 7) << 4)))        = u0;
        *reinterpret_cast<uint4*>(sm + OFF_A + ((b0 + 16) ^ ((e & 7) << 4))) = u1;
    }

    run_layer< 64, 256, 1>(sm, Bpp + 0,      OFF_A, OFF_B, b1,  w, lane);
    run_layer<256, 128, 1>(sm, Bpp + 65536,  OFF_B, OFF_A, b2,  w, lane);
    run_layer<128,  64, 0>(sm, Bpp + 196608, OFF_A, OFF_B, b3,  w, lane);
    run_layer< 64,  64, 1>(sm, Bpp + 229376, OFF_B, OFF_A, pb1, w, lane);
    __syncthreads();   // P1 output (region A) complete

    // P2 (64 -> 16, only col sCol[row] needed): wave 0 only, direct register extraction
    if (w == 0) {
        const int row0 = lane & 15;
        const int hi16 = (lane >> 4) * 16;
        const char* gB = Bpp + 245760;
        f32x4 C[4];
        float b = (row0 < 10) ? pb2[row0] : 0.f;
        #pragma unroll
        for (int mt = 0; mt < 4; ++mt) C[mt] = (f32x4){b, b, b, b};
        #pragma unroll
        for (int kb = 0; kb < 2; ++kb) {
            f16x8 Ah[4];
            #pragma unroll
            for (int mt = 0; mt < 4; ++mt) {
                int row = mt * 16 + row0;
                int off = (((row * 64 + kb * 32) * 2) + hi16) ^ ((row & 7) << 4);
                Ah[mt] = *reinterpret_cast<const f16x8*>(sm + OFF_A + off);
            }
            f16x8 Bh = *reinterpret_cast<const f16x8*>(gB + kb * 1024 + lane * 16);
            #pragma unroll
            for (int mt = 0; mt < 4; ++mt)
                C[mt] = __builtin_amdgcn_mfma_f32_16x16x32_f16(Ah[mt], Bh, C[mt], 0, 0, 0);
        }
        #pragma unroll
        for (int mt = 0; mt < 4; ++mt) {
            #pragma unroll
            for (int r = 0; r < 4; ++r) {
                int row = mt * 16 + (lane >> 4) * 4 + r;
                if (row0 == sCol[row]) {
                    float lg = C[mt][r];
                    lg_out[ebase + row] = lg;
                    float lgm = sAvail[row] ? lg : -INFINITY;
                    atomicMax(&m_u[sG[row]], enc_f(lgm));
                }
            }
        }
    }
}

// ---------- 4) exp + LDS-bucketed denom + candidate select ----------
__global__ void k_ex(const float* __restrict__ lg, const unsigned short* __restrict__ meta,
                     const unsigned* __restrict__ m_u, float* __restrict__ ex,
                     float* __restrict__ denom, unsigned* __restrict__ cand,
                     unsigned* __restrict__ ccnt)
{
    __shared__ float sden[N_GRAPHS];
    for (int i = threadIdx.x; i < N_GRAPHS; i += 256) sden[i] = 0.f;
    __syncthreads();
    for (int e = blockIdx.x * 256 + threadIdx.x; e < N_EDGES; e += gridDim.x * 256) {
        unsigned mt_ = meta[e];
        int g = mt_ & 0x1ff;
        float v = 0.f;
        if (mt_ & 0x8000) {
            float l = lg[e];
            float m = dec_f(m_u[g]);
            v = __expf(l - m);
            if (l >= m - DELTA) {
                unsigned i = atomicAdd(ccnt, 1u);
                if (i < CAND_MAX) cand[i] = (unsigned)e;
            }
        }
        ex[e] = v;
        atomicAdd(&sden[g], v);
    }
    __syncthreads();
    for (int i = threadIdx.x; i < N_GRAPHS; i += 256)
        if (sden[i] != 0.f) atomicAdd(&denom[i], sden[i]);
}

// ---------- 5) probs prologue + exact f32 recompute for ALL candidates + u64-key argmax ----------
__global__ __launch_bounds__(256) void k_refine(
    const float* __restrict__ reps, const int* __restrict__ src, const int* __restrict__ dst,
    const unsigned short* __restrict__ meta, const int* __restrict__ y,
    const float* __restrict__ Wt,
    const float* __restrict__ b1, const float* __restrict__ b2, const float* __restrict__ b3,
    const float* __restrict__ pb1, const float* __restrict__ P2, const float* __restrict__ pb2,
    const float* __restrict__ ex, const float* __restrict__ denom, float* __restrict__ out,
    const unsigned* __restrict__ cand, const unsigned* __restrict__ ccnt,
    unsigned long long* __restrict__ key)
{
    // --- probs: grid-stride over all edges ---
    for (int e = blockIdx.x * 256 + threadIdx.x; e < N_EDGES; e += gridDim.x * 256)
        out[e] = ex[e] / denom[meta[e] & 0x1ff];

    __shared__ float sa[4][256], sb[4][256];
    const int t = threadIdx.x, w = t >> 6, lane = t & 63;
    const float* W1t = Wt;            // [256][64]
    const float* W2t = Wt + 16384;    // [128][256]
    const float* W3t = Wt + 49152;    // [64][128]
    const float* P1t = Wt + 57344;    // [64][64]
    unsigned cnt = *ccnt; if (cnt > CAND_MAX) cnt = CAND_MAX;
    for (unsigned base = blockIdx.x * 4; base < cnt; base += gridDim.x * 4) {
        unsigned ci = base + w;
        bool act = ci < cnt;
        int g = 0, col = 0; unsigned e = 0;
        if (act) {
            e = cand[ci];
            int s_ = src[e], d_ = dst[e];
            g = meta[e] & 0x1ff; col = y[g];
            sa[w][lane] = (lane < 32) ? reps[s_ * 32 + lane] : reps[d_ * 32 + (lane - 32)];
        }
        __syncthreads();
        // L1: 64 -> 256
        {
            float acc[4];
            #pragma unroll
            for (int r = 0; r < 4; ++r) acc[r] = b1[lane + 64 * r];
            #pragma unroll
            for (int k = 0; k < 64; k += 4) {
                float4 a = *reinterpret_cast<const float4*>(&sa[w][k]);
                #pragma unroll
                for (int r = 0; r < 4; ++r) {
                    float4 wv = *reinterpret_cast<const float4*>(&W1t[(lane + 64 * r) * 64 + k]);
                    acc[r] += a.x * wv.x + a.y * wv.y + a.z * wv.z + a.w * wv.w;
                }
            }
            #pragma unroll
            for (int r = 0; r < 4; ++r) sb[w][lane + 64 * r] = elu_f(acc[r]);
        }
        __syncthreads();
        // L2: 256 -> 128
        {
            float acc0 = b2[lane], acc1 = b2[lane + 64];
            #pragma unroll
            for (int k = 0; k < 256; k += 4) {
                float4 a = *reinterpret_cast<const float4*>(&sb[w][k]);
                float4 w0 = *reinterpret_cast<const float4*>(&W2t[lane * 256 + k]);
                float4 w1 = *reinterpret_cast<const float4*>(&W2t[(lane + 64) * 256 + k]);
                acc0 += a.x * w0.x + a.y * w0.y + a.z * w0.z + a.w * w0.w;
                acc1 += a.x * w1.x + a.y * w1.y + a.z * w1.z + a.w * w1.w;
            }
            sa[w][lane] = elu_f(acc0); sa[w][lane + 64] = elu_f(acc1);
        }
        __syncthreads();
        // L3: 128 -> 64 (no act)
        {
            float acc = b3[lane];
            #pragma unroll
            for (int k = 0; k < 128; k += 4) {
                float4 a = *reinterpret_cast<const float4*>(&sa[w][k]);
                float4 wv = *reinterpret_cast<const float4*>(&W3t[lane * 128 + k]);
                acc += a.x * wv.x + a.y * wv.y + a.z * wv.z + a.w * wv.w;
            }
            sb[w][lane] = acc;
        }
        __syncthreads();
        // P1: 64 -> 64 + elu, then P2 col dot
        float p1o;
        {
            float acc = pb1[lane];
            #pragma unroll
            for (int k = 0; k < 64; k += 4) {
                float4 a = *reinterpret_cast<const float4*>(&sb[w][k]);
                float4 wv = *reinterpret_cast<const float4*>(&P1t[lane * 64 + k]);
                acc += a.x * wv.x + a.y * wv.y + a.z * wv.z + a.w * wv.w;
            }
            p1o = elu_f(acc);
        }
        float part = act ? p1o * P2[lane * 10 + col] : 0.f;
        #pragma unroll
        for (int m = 32; m > 0; m >>= 1) part += __shfl_xor(part, m, 64);
        if (act && lane == 0) {
            float lgf = part + pb2[col];
            unsigned long long k64 = ((unsigned long long)enc_f(lgf) << 32) | (unsigned)(~e);
            atomicMax(&key[g], k64);
        }
        __syncthreads();
    }
}

// ---------- 6) finalize ----------
__global__ void k_final(const float* __restrict__ denom, const unsigned long long* __restrict__ key,
                        float* __restrict__ out)
{
    int g = blockIdx.x * 256 + threadIdx.x;
    if (g >= N_GRAPHS) return;
    out[N_EDGES + g] = 1.0f / denom[g];
    unsigned long long k = key[g];
    out[N_EDGES + N_GRAPHS + g] = (float)(~(unsigned)(k & 0xFFFFFFFFull));
}

// ---------- launch ----------
extern "C" void kernel_launch(void* const* d_in, const int* in_sizes, int n_in,
                              void* d_out, int out_size, void* d_ws, size_t ws_size,
                              hipStream_t stream)
{
    const float* x   = (const float*)d_in[0];
    const int*   ei  = (const int*)d_in[1];
    const int*   src = ei;
    const int*   dst = ei + N_EDGES;
    const unsigned char* state = (const unsigned char*)d_in[2];
    const int*   batch = (const int*)d_in[3];
    const int*   y     = (const int*)d_in[4];
    const float* Wg = (const float*)d_in[5];
    const float* bg = (const float*)d_in[6];
    const float* W1 = (const float*)d_in[7];
    const float* b1 = (const float*)d_in[8];
    const float* W2 = (const float*)d_in[9];
    const float* b2 = (const float*)d_in[10];
    const float* W3 = (const float*)d_in[11];
    const float* b3 = (const float*)d_in[12];
    const float* P1 = (const float*)d_in[13];
    const float* pb1= (const float*)d_in[14];
    const float* P2 = (const float*)d_in[15];
    const float* pb2= (const float*)d_in[16];

    float* ws = (float*)d_ws;
    unsigned*           bucket = (unsigned*)ws;                       // 3,200,000 u32
    unsigned*           cnt    = (unsigned*)(ws + 3200000);           //    50,000 u32
    unsigned*           m_u    = (unsigned*)(ws + 3250000);           // 500
    float*              denom  = (float*)(ws + 3250500);              // 500
    unsigned*           ccnt   = (unsigned*)(ws + 3251000);           // 1 (+1 pad)
    unsigned long long* key    = (unsigned long long*)(ws + 3251002); // 500 u64 (8B-aligned)
    float*              reps   = ws + 3252004;                        // 1,600,000 f32
    float*              lg     = ws + 4852004;                        //   400,000 f32
    float*              ex     = ws + 5252004;                        //   400,000 f32
    unsigned short*     meta   = (unsigned short*)(ws + 5652004);     //   400,000 u16
    char*               Bpp    = (char*)(ws + 5852004);               // 249,856 B (16B-aligned)
    unsigned*           cand   = (unsigned*)(ws + 5914468);           // 262,144 u32
    float*              Wt     = ws + 6176612;                        //  61,440 f32 (16B-aligned)

    // single zero memset: cnt + m_u + denom + ccnt + pad + key (contiguous)
    hipMemsetAsync(cnt, 0, (size_t)(3252002 - 3200000) * 4, stream);

    k_place  <<<1864, 256, 0, stream>>>(src, dst, state, batch, cnt, bucket, meta,
                                        W1, W2, W3, P1, P2, Bpp, Wt);
    k_aggrep <<<N_NODES / 4, 256, 0, stream>>>(x, cnt, bucket, Wg, bg, reps);
    k_mlp    <<<N_EDGES / 64, 256, 0, stream>>>(reps, src, dst, meta, y,
                                                b1, b2, b3, pb1, pb2, Bpp, lg, m_u);
    k_ex     <<<256, 256, 0, stream>>>(lg, meta, m_u, ex, denom, cand, ccnt);
    k_refine <<<1024, 256, 0, stream>>>(reps, src, dst, meta, y, Wt,
                                        b1, b2, b3, pb1, P2, pb2,
                                        ex, denom, (float*)d_out,
                                        cand, ccnt, key);
    k_final  <<<2, 256, 0, stream>>>(denom, key, (float*)d_out);
}

// Round 15
// 347.993 us; speedup vs baseline: 1.3062x; 1.3062x over previous
//
#include <hip/hip_runtime.h>
#include <math.h>

#define N_NODES   50000
#define N_EDGES   400000
#define N_GRAPHS  500
#define CAND_MAX  262144
#define DELTA     8e-3f
#define CAP       64

typedef __attribute__((ext_vector_type(8))) _Float16 f16x8;
typedef __attribute__((ext_vector_type(4))) float f32x4;

// ---------- helpers ----------
__device__ __forceinline__ float elu_f(float v) { return v > 0.f ? v : expm1f(v); }   // exact-refine grade
__device__ __forceinline__ float elu_fast(float v) {
    return fmaxf(v, 0.f) + (__expf(fminf(v, 0.f)) - 1.f);
}
__device__ __forceinline__ unsigned enc_f(float f) {
    unsigned u = __float_as_uint(f);
    return (u & 0x80000000u) ? ~u : (u | 0x80000000u);
}
__device__ __forceinline__ float dec_f(unsigned u) {
    return __uint_as_float((u & 0x80000000u) ? (u & 0x7FFFFFFFu) : ~u);
}
__device__ __forceinline__ unsigned short f2h_bits(float f) {
    _Float16 h = (_Float16)f;
    return __builtin_bit_cast(unsigned short, h);
}
__device__ __forceinline__ float h2f(unsigned short b) {
    return (float)__builtin_bit_cast(_Float16, b);
}

// ---------- 1) bucket placement + meta + weight prep + f32 transpose (fused) ----------
__global__ void k_place(const int* __restrict__ src, const int* __restrict__ dst,
                        const unsigned char* __restrict__ state, const int* __restrict__ batch,
                        unsigned* __restrict__ cnt, unsigned* __restrict__ bucket,
                        unsigned short* __restrict__ meta,
                        const float* __restrict__ W1, const float* __restrict__ W2,
                        const float* __restrict__ W3, const float* __restrict__ P1,
                        const float* __restrict__ P2, char* __restrict__ Bpp,
                        float* __restrict__ Wt)
{
    if (blockIdx.x < 1563) {
        int e = blockIdx.x * 256 + threadIdx.x;
        if (e >= N_EDGES) return;
        int d = dst[e];
        int s = src[e];
        unsigned char st = state[e];
        unsigned idx = atomicAdd(&cnt[d], 1u);
        if (idx < CAP) bucket[d * CAP + idx] = (unsigned)s | (st ? 0x80000000u : 0u);
        int g = batch[s];
        meta[e] = (unsigned short)(g | (st ? 0 : 0x8000));
        return;
    }
    if (blockIdx.x >= 1624) {
        // ---- f32 transposed weights for the exact-refine arbiter ----
        int t2 = (blockIdx.x - 1624) * 256 + threadIdx.x;   // 0..61439
        if (t2 < 16384)      Wt[t2]         = W1[(t2 % 64) * 256 + t2 / 64];                 // W1t [256][64]
        else if (t2 < 49152) { int t = t2 - 16384; Wt[t2] = W2[(t % 256) * 128 + t / 256]; } // W2t [128][256]
        else if (t2 < 57344) { int t = t2 - 49152; Wt[t2] = W3[(t % 128) * 64 + t / 128]; }  // W3t [64][128]
        else                 { int t = t2 - 57344; Wt[t2] = P1[(t % 64) * 64 + t / 64]; }    // P1t [64][64]
        return;
    }
    // ---- weight prep: split f32 -> (Wh, Wl) f16, fragment-ordered (lo plane kept for layout compat) ----
    int tid = (blockIdx.x - 1563) * 256 + threadIdx.x;
    if (tid >= 15616) return;
    const float* W; int K, NT, Nreal, base, i;
    if (tid < 4096)       { W = W1; K = 64;  NT = 16; Nreal = 256; base = 0;      i = tid; }
    else if (tid < 12288) { W = W2; K = 256; NT = 8;  Nreal = 128; base = 65536;  i = tid - 4096; }
    else if (tid < 14336) { W = W3; K = 128; NT = 4;  Nreal = 64;  base = 196608; i = tid - 12288; }
    else if (tid < 15360) { W = P1; K = 64;  NT = 4;  Nreal = 64;  base = 229376; i = tid - 14336; }
    else                  { W = P2; K = 64;  NT = 1;  Nreal = 10;  base = 245760; i = tid - 15360; }
    int KB = K / 32;
    int lane = i & 63; int i2 = i >> 6;
    int nt = i2 % NT; int i3 = i2 / NT;
    int kb = i3 % KB; int ps = i3 / KB;
    unsigned short s[8];
    #pragma unroll
    for (int j = 0; j < 8; ++j) {
        int k = kb * 32 + ((lane >> 4) << 3) + j;
        int n = nt * 16 + (lane & 15);
        float wv = (n < Nreal) ? W[k * Nreal + n] : 0.f;
        unsigned short h = f2h_bits(wv);
        s[j] = ps ? f2h_bits(wv - h2f(h)) : h;
    }
    uint4 u;
    u.x = (unsigned)s[0] | ((unsigned)s[1] << 16);
    u.y = (unsigned)s[2] | ((unsigned)s[3] << 16);
    u.z = (unsigned)s[4] | ((unsigned)s[5] << 16);
    u.w = (unsigned)s[6] | ((unsigned)s[7] << 16);
    int frag = (ps * KB + kb) * NT + nt;
    *reinterpret_cast<uint4*>(Bpp + base + frag * 1024 + lane * 16) = u;
}

// ---------- 2) fused gather-aggregate + node reps (chunked gathers, same FP order) ----------
__global__ void k_aggrep(const float* __restrict__ x, const unsigned* __restrict__ cnt,
                         const unsigned* __restrict__ bucket, const float* __restrict__ Wg,
                         const float* __restrict__ bg, float* __restrict__ reps)
{
    __shared__ float sv[4][128];
    const int w = threadIdx.x >> 6, j = threadIdx.x & 63;
    const int n = blockIdx.x * 4 + w;
    unsigned c = cnt[n]; if (c > CAP) c = CAP;
    float sf = 0.f, so = 0.f;
    unsigned i = 0;
    for (; i + 4 <= c; i += 4) {
        unsigned p0 = bucket[n * CAP + i];
        unsigned p1 = bucket[n * CAP + i + 1];
        unsigned p2 = bucket[n * CAP + i + 2];
        unsigned p3 = bucket[n * CAP + i + 3];
        float v0 = x[(p0 & 0x7FFFFFFFu) * 64 + j];
        float v1 = x[(p1 & 0x7FFFFFFFu) * 64 + j];
        float v2 = x[(p2 & 0x7FFFFFFFu) * 64 + j];
        float v3 = x[(p3 & 0x7FFFFFFFu) * 64 + j];
        sf += v0; if (p0 & 0x80000000u) so += v0;
        sf += v1; if (p1 & 0x80000000u) so += v1;
        sf += v2; if (p2 & 0x80000000u) so += v2;
        sf += v3; if (p3 & 0x80000000u) so += v3;
    }
    for (; i < c; ++i) {
        unsigned p = bucket[n * CAP + i];
        float v = x[(p & 0x7FFFFFFFu) * 64 + j];
        sf += v;
        if (p & 0x80000000u) so += v;
    }
    float xv = x[n * 64 + j];
    sv[w][j]      = xv + sf;
    sv[w][64 + j] = xv + so;
    __syncthreads();
    const int o = j & 31;
    const float* svp = sv[w] + ((j >> 5) ? 64 : 0);
    float acc = 0.f;
    #pragma unroll 16
    for (int i2 = 0; i2 < 64; ++i2) acc += svp[i2] * Wg[i2 * 32 + o];
    float val = elu_fast(acc + bg[o]);
    float other = __shfl_xor(val, 32, 64);
    if (j < 32) reps[n * 32 + o] = val - other;
}

// ---------- 3) fused MFMA MLP: 64 edges/block, f16 hi-only acts, HI-ONLY weights (r13 form) ----------
// LDS rotation: region A 16 KB @0, region B 32 KB @16384 -> 48 KB -> 3 blocks/CU.
#define OFF_A 0
#define OFF_B 16384
#define SM_BYTES 49152

template<int K, int N, int ACT>   // ACT: 0 linear, 1 elu, 2 logits f32 store
__device__ __forceinline__ void run_layer(char* sm, const char* gB, int inOff, int outOff,
                                          const float* __restrict__ bias, int w, int lane)
{
    constexpr int KB  = K / 32;
    constexpr int NT  = N / 16;
    constexpr int NTC = (NT < 8) ? NT : 8;
    constexpr int NH  = NT / NTC;
    constexpr int NTW = (NTC >= 4) ? (NTC / 4) : 1;

    __syncthreads();

    const int row0 = lane & 15;
    const int hi16 = (lane >> 4) * 16;   // byte offset of k-subgroup

    #pragma unroll
    for (int nh = 0; nh < NH; ++nh) {
        f32x4 C[4][NTW];
        #pragma unroll
        for (int q = 0; q < NTW; ++q) {
            int nt = (w * NTW + q) % NTC;
            int n  = nh * NTC * 16 + nt * 16 + row0;
            float b = (ACT == 2) ? (n < 10 ? bias[n] : 0.f) : bias[n];
            #pragma unroll
            for (int mt = 0; mt < 4; ++mt) C[mt][q] = (f32x4){b, b, b, b};
        }

        #pragma unroll
        for (int kb = 0; kb < KB; ++kb) {
            f16x8 Ah[4];
            #pragma unroll
            for (int mt = 0; mt < 4; ++mt) {
                int row = mt * 16 + row0;
                int off = (((row * K + kb * 32) * 2) + hi16) ^ ((row & 7) << 4);
                Ah[mt] = *reinterpret_cast<const f16x8*>(sm + inOff + off);
            }
            #pragma unroll
            for (int q = 0; q < NTW; ++q) {
                int nt = (w * NTW + q) % NTC;
                const char* bp = gB + ((kb * NT + nh * NTC + nt) * 1024) + lane * 16;
                f16x8 Bh = *reinterpret_cast<const f16x8*>(bp);
                #pragma unroll
                for (int mt = 0; mt < 4; ++mt)
                    C[mt][q] = __builtin_amdgcn_mfma_f32_16x16x32_f16(Ah[mt], Bh, C[mt][q], 0, 0, 0);
            }
        }

        // epilogue (hi-only f16 store, or f32 for logits)
        #pragma unroll
        for (int q = 0; q < NTW; ++q) {
            int nt = (w * NTW + q) % NTC;
            int n  = nh * NTC * 16 + nt * 16 + row0;
            #pragma unroll
            for (int mt = 0; mt < 4; ++mt) {
                #pragma unroll
                for (int r = 0; r < 4; ++r) {
                    int row = mt * 16 + (lane >> 4) * 4 + r;
                    float v = C[mt][q][r];
                    if (ACT == 1) v = elu_fast(v);
                    if (ACT == 2) {
                        *reinterpret_cast<float*>(sm + outOff + (row * 16 + n) * 4) = v;
                    } else {
                        int off = ((row * N + n) * 2) ^ ((row & 7) << 4);
                        *reinterpret_cast<unsigned short*>(sm + outOff + off) = f2h_bits(v);
                    }
                }
            }
        }
    }
}

__global__ __launch_bounds__(256, 3) void k_mlp(
    const float* __restrict__ reps, const int* __restrict__ src, const int* __restrict__ dst,
    const unsigned short* __restrict__ meta, const int* __restrict__ y,
    const float* __restrict__ b1, const float* __restrict__ b2, const float* __restrict__ b3,
    const float* __restrict__ pb1, const float* __restrict__ pb2,
    const char* __restrict__ Bpp, float* __restrict__ lg_out, unsigned* __restrict__ m_u)
{
    __shared__ char sm[SM_BYTES];
    __shared__ int sSrc[64], sDst[64], sG[64], sCol[64], sAvail[64];
    const int t = threadIdx.x, w = t >> 6, lane = t & 63;
    const int ebase = blockIdx.x * 64;

    if (t < 64) {
        int e = ebase + t;
        sSrc[t] = src[e]; sDst[t] = dst[e];
        unsigned m = meta[e];
        int g = m & 0x1ff;
        sG[t] = g; sCol[t] = y[g];
        sAvail[t] = (m >> 15) & 1;
    }
    __syncthreads();

    // stage input tile: concat(reps[src], reps[dst]) -> f16, swizzled -> region A
    {
        int e = t >> 2, f0 = (t & 3) * 16;
        const float* rp = (f0 < 32) ? (reps + sSrc[e] * 32 + f0) : (reps + sDst[e] * 32 + (f0 - 32));
        float4 v0 = *reinterpret_cast<const float4*>(rp);
        float4 v1 = *reinterpret_cast<const float4*>(rp + 4);
        float4 v2 = *reinterpret_cast<const float4*>(rp + 8);
        float4 v3 = *reinterpret_cast<const float4*>(rp + 12);
        float vv[16] = {v0.x,v0.y,v0.z,v0.w, v1.x,v1.y,v1.z,v1.w,
                        v2.x,v2.y,v2.z,v2.w, v3.x,v3.y,v3.z,v3.w};
        unsigned pk[8];
        #pragma unroll
        for (int i = 0; i < 8; ++i)
            pk[i] = (unsigned)f2h_bits(vv[2*i]) | ((unsigned)f2h_bits(vv[2*i+1]) << 16);
        int b0 = (e * 64 + f0) * 2;
        uint4 u0 = {pk[0], pk[1], pk[2], pk[3]};
        uint4 u1 = {pk[4], pk[5], pk[6], pk[7]};
        *reinterpret_cast<uint4*>(sm + OFF_A + (b0 ^ ((e & 7) << 4)))        = u0;
        *reinterpret_cast<uint4*>(sm + OFF_A + ((b0 + 16) ^ ((e & 7) << 4))) = u1;
    }

    run_layer< 64, 256, 1>(sm, Bpp + 0,      OFF_A, OFF_B, b1,  w, lane);
    run_layer<256, 128, 1>(sm, Bpp + 65536,  OFF_B, OFF_A, b2,  w, lane);
    run_layer<128,  64, 0>(sm, Bpp + 196608, OFF_A, OFF_B, b3,  w, lane);
    run_layer< 64,  64, 1>(sm, Bpp + 229376, OFF_B, OFF_A, pb1, w, lane);
    run_layer< 64,  16, 2>(sm, Bpp + 245760, OFF_A, OFF_B, pb2, w, lane);
    __syncthreads();

    if (t < 64) {
        int col = sCol[t];
        float lg = *reinterpret_cast<const float*>(sm + OFF_B + (t * 16 + col) * 4);
        lg_out[ebase + t] = lg;
        float lgm = sAvail[t] ? lg : -INFINITY;
        atomicMax(&m_u[sG[t]], enc_f(lgm));
    }
}

// ---------- 4) exp + LDS-bucketed denom + candidate select ----------
__global__ void k_ex(const float* __restrict__ lg, const unsigned short* __restrict__ meta,
                     const unsigned* __restrict__ m_u, float* __restrict__ ex,
                     float* __restrict__ denom, unsigned* __restrict__ cand,
                     unsigned* __restrict__ ccnt)
{
    __shared__ float sden[N_GRAPHS];
    for (int i = threadIdx.x; i < N_GRAPHS; i += 256) sden[i] = 0.f;
    __syncthreads();
    for (int e = blockIdx.x * 256 + threadIdx.x; e < N_EDGES; e += gridDim.x * 256) {
        unsigned mt_ = meta[e];
        int g = mt_ & 0x1ff;
        float v = 0.f;
        if (mt_ & 0x8000) {
            float l = lg[e];
            float m = dec_f(m_u[g]);
            v = __expf(l - m);
            if (l >= m - DELTA) {
                unsigned i = atomicAdd(ccnt, 1u);
                if (i < CAND_MAX) cand[i] = (unsigned)e;
            }
        }
        ex[e] = v;
        atomicAdd(&sden[g], v);
    }
    __syncthreads();
    for (int i = threadIdx.x; i < N_GRAPHS; i += 256)
        if (sden[i] != 0.f) atomicAdd(&denom[i], sden[i]);
}

// ---------- 5) probs prologue + exact f32 recompute for ALL candidates + u64-key argmax ----------
__global__ __launch_bounds__(256) void k_refine(
    const float* __restrict__ reps, const int* __restrict__ src, const int* __restrict__ dst,
    const unsigned short* __restrict__ meta, const int* __restrict__ y,
    const float* __restrict__ Wt,
    const float* __restrict__ b1, const float* __restrict__ b2, const float* __restrict__ b3,
    const float* __restrict__ pb1, const float* __restrict__ P2, const float* __restrict__ pb2,
    const float* __restrict__ ex, const float* __restrict__ denom, float* __restrict__ out,
    const unsigned* __restrict__ cand, const unsigned* __restrict__ ccnt,
    unsigned long long* __restrict__ key)
{
    // --- probs: grid-stride over all edges ---
    for (int e = blockIdx.x * 256 + threadIdx.x; e < N_EDGES; e += gridDim.x * 256)
        out[e] = ex[e] / denom[meta[e] & 0x1ff];

    __shared__ float sa[4][256], sb[4][256];
    const int t = threadIdx.x, w = t >> 6, lane = t & 63;
    const float* W1t = Wt;            // [256][64]
    const float* W2t = Wt + 16384;    // [128][256]
    const float* W3t = Wt + 49152;    // [64][128]
    const float* P1t = Wt + 57344;    // [64][64]
    unsigned cnt = *ccnt; if (cnt > CAND_MAX) cnt = CAND_MAX;
    for (unsigned base = blockIdx.x * 4; base < cnt; base += gridDim.x * 4) {
        unsigned ci = base + w;
        bool act = ci < cnt;
        int g = 0, col = 0; unsigned e = 0;
        if (act) {
            e = cand[ci];
            int s_ = src[e], d_ = dst[e];
            g = meta[e] & 0x1ff; col = y[g];
            sa[w][lane] = (lane < 32) ? reps[s_ * 32 + lane] : reps[d_ * 32 + (lane - 32)];
        }
        __syncthreads();
        // L1: 64 -> 256
        {
            float acc[4];
            #pragma unroll
            for (int r = 0; r < 4; ++r) acc[r] = b1[lane + 64 * r];
            #pragma unroll
            for (int k = 0; k < 64; k += 4) {
                float4 a = *reinterpret_cast<const float4*>(&sa[w][k]);
                #pragma unroll
                for (int r = 0; r < 4; ++r) {
                    float4 wv = *reinterpret_cast<const float4*>(&W1t[(lane + 64 * r) * 64 + k]);
                    acc[r] += a.x * wv.x + a.y * wv.y + a.z * wv.z + a.w * wv.w;
                }
            }
            #pragma unroll
            for (int r = 0; r < 4; ++r) sb[w][lane + 64 * r] = elu_f(acc[r]);
        }
        __syncthreads();
        // L2: 256 -> 128
        {
            float acc0 = b2[lane], acc1 = b2[lane + 64];
            #pragma unroll
            for (int k = 0; k < 256; k += 4) {
                float4 a = *reinterpret_cast<const float4*>(&sb[w][k]);
                float4 w0 = *reinterpret_cast<const float4*>(&W2t[lane * 256 + k]);
                float4 w1 = *reinterpret_cast<const float4*>(&W2t[(lane + 64) * 256 + k]);
                acc0 += a.x * w0.x + a.y * w0.y + a.z * w0.z + a.w * w0.w;
                acc1 += a.x * w1.x + a.y * w1.y + a.z * w1.z + a.w * w1.w;
            }
            sa[w][lane] = elu_f(acc0); sa[w][lane + 64] = elu_f(acc1);
        }
        __syncthreads();
        // L3: 128 -> 64 (no act)
        {
            float acc = b3[lane];
            #pragma unroll
            for (int k = 0; k < 128; k += 4) {
                float4 a = *reinterpret_cast<const float4*>(&sa[w][k]);
                float4 wv = *reinterpret_cast<const float4*>(&W3t[lane * 128 + k]);
                acc += a.x * wv.x + a.y * wv.y + a.z * wv.z + a.w * wv.w;
            }
            sb[w][lane] = acc;
        }
        __syncthreads();
        // P1: 64 -> 64 + elu, then P2 col dot
        float p1o;
        {
            float acc = pb1[lane];
            #pragma unroll
            for (int k = 0; k < 64; k += 4) {
                float4 a = *reinterpret_cast<const float4*>(&sb[w][k]);
                float4 wv = *reinterpret_cast<const float4*>(&P1t[lane * 64 + k]);
                acc += a.x * wv.x + a.y * wv.y + a.z * wv.z + a.w * wv.w;
            }
            p1o = elu_f(acc);
        }
        float part = act ? p1o * P2[lane * 10 + col] : 0.f;
        #pragma unroll
        for (int m = 32; m > 0; m >>= 1) part += __shfl_xor(part, m, 64);
        if (act && lane == 0) {
            float lgf = part + pb2[col];
            unsigned long long k64 = ((unsigned long long)enc_f(lgf) << 32) | (unsigned)(~e);
            atomicMax(&key[g], k64);
        }
        __syncthreads();
    }
}

// ---------- 6) finalize ----------
__global__ void k_final(const float* __restrict__ denom, const unsigned long long* __restrict__ key,
                        float* __restrict__ out)
{
    int g = blockIdx.x * 256 + threadIdx.x;
    if (g >= N_GRAPHS) return;
    out[N_EDGES + g] = 1.0f / denom[g];
    unsigned long long k = key[g];
    out[N_EDGES + N_GRAPHS + g] = (float)(~(unsigned)(k & 0xFFFFFFFFull));
}

// ---------- launch ----------
extern "C" void kernel_launch(void* const* d_in, const int* in_sizes, int n_in,
                              void* d_out, int out_size, void* d_ws, size_t ws_size,
                              hipStream_t stream)
{
    const float* x   = (const float*)d_in[0];
    const int*   ei  = (const int*)d_in[1];
    const int*   src = ei;
    const int*   dst = ei + N_EDGES;
    const unsigned char* state = (const unsigned char*)d_in[2];
    const int*   batch = (const int*)d_in[3];
    const int*   y     = (const int*)d_in[4];
    const float* Wg = (const float*)d_in[5];
    const float* bg = (const float*)d_in[6];
    const float* W1 = (const float*)d_in[7];
    const float* b1 = (const float*)d_in[8];
    const float* W2 = (const float*)d_in[9];
    const float* b2 = (const float*)d_in[10];
    const float* W3 = (const float*)d_in[11];
    const float* b3 = (const float*)d_in[12];
    const float* P1 = (const float*)d_in[13];
    const float* pb1= (const float*)d_in[14];
    const float* P2 = (const float*)d_in[15];
    const float* pb2= (const float*)d_in[16];

    float* ws = (float*)d_ws;
    unsigned*           bucket = (unsigned*)ws;                       // 3,200,000 u32
    unsigned*           cnt    = (unsigned*)(ws + 3200000);           //    50,000 u32
    unsigned*           m_u    = (unsigned*)(ws + 3250000);           // 500
    float*              denom  = (float*)(ws + 3250500);              // 500
    unsigned*           ccnt   = (unsigned*)(ws + 3251000);           // 1 (+1 pad)
    unsigned long long* key    = (unsigned long long*)(ws + 3251002); // 500 u64 (8B-aligned)
    float*              reps   = ws + 3252004;                        // 1,600,000 f32
    float*              lg     = ws + 4852004;                        //   400,000 f32
    float*              ex     = ws + 5252004;                        //   400,000 f32
    unsigned short*     meta   = (unsigned short*)(ws + 5652004);     //   400,000 u16
    char*               Bpp    = (char*)(ws + 5852004);               // 249,856 B (16B-aligned)
    unsigned*           cand   = (unsigned*)(ws + 5914468);           // 262,144 u32
    float*              Wt     = ws + 6176612;                        //  61,440 f32 (16B-aligned)

    // single zero memset: cnt + m_u + denom + ccnt + pad + key (contiguous)
    hipMemsetAsync(cnt, 0, (size_t)(3252002 - 3200000) * 4, stream);

    k_place  <<<1864, 256, 0, stream>>>(src, dst, state, batch, cnt, bucket, meta,
                                        W1, W2, W3, P1, P2, Bpp, Wt);
    k_aggrep <<<N_NODES / 4, 256, 0, stream>>>(x, cnt, bucket, Wg, bg, reps);
    k_mlp    <<<N_EDGES / 64, 256, 0, stream>>>(reps, src, dst, meta, y,
                                                b1, b2, b3, pb1, pb2, Bpp, lg, m_u);
    k_ex     <<<256, 256, 0, stream>>>(lg, meta, m_u, ex, denom, cand, ccnt);
    k_refine <<<1024, 256, 0, stream>>>(reps, src, dst, meta, y, Wt,
                                        b1, b2, b3, pb1, P2, pb2,
                                        ex, denom, (float*)d_out,
                                        cand, ccnt, key);
    k_final  <<<2, 256, 0, stream>>>(denom, key, (float*)d_out);
}

// Round 16
// 347.597 us; speedup vs baseline: 1.3077x; 1.0011x over previous
//
#include <hip/hip_runtime.h>
#include <math.h>

#define N_NODES   50000
#define N_EDGES   400000
#define N_GRAPHS  500
#define CAND_MAX  262144
#define DELTA     8e-3f
#define CAP       64

typedef __attribute__((ext_vector_type(8))) _Float16 f16x8;
typedef __attribute__((ext_vector_type(4))) float f32x4;

// ---------- helpers ----------
__device__ __forceinline__ float elu_f(float v) { return v > 0.f ? v : expm1f(v); }   // exact-refine grade
__device__ __forceinline__ float elu_fast(float v) {
    return fmaxf(v, 0.f) + (__expf(fminf(v, 0.f)) - 1.f);
}
__device__ __forceinline__ unsigned enc_f(float f) {
    unsigned u = __float_as_uint(f);
    return (u & 0x80000000u) ? ~u : (u | 0x80000000u);
}
__device__ __forceinline__ float dec_f(unsigned u) {
    return __uint_as_float((u & 0x80000000u) ? (u & 0x7FFFFFFFu) : ~u);
}
__device__ __forceinline__ unsigned short f2h_bits(float f) {
    _Float16 h = (_Float16)f;
    return __builtin_bit_cast(unsigned short, h);
}
__device__ __forceinline__ float h2f(unsigned short b) {
    return (float)__builtin_bit_cast(_Float16, b);
}

// ---------- 1) bucket placement + meta + weight prep + f32 transpose (fused) ----------
__global__ void k_place(const int* __restrict__ src, const int* __restrict__ dst,
                        const unsigned char* __restrict__ state, const int* __restrict__ batch,
                        unsigned* __restrict__ cnt, unsigned* __restrict__ bucket,
                        unsigned short* __restrict__ meta,
                        const float* __restrict__ W1, const float* __restrict__ W2,
                        const float* __restrict__ W3, const float* __restrict__ P1,
                        const float* __restrict__ P2, char* __restrict__ Bpp,
                        float* __restrict__ Wt)
{
    if (blockIdx.x < 1563) {
        int e = blockIdx.x * 256 + threadIdx.x;
        if (e >= N_EDGES) return;
        int d = dst[e];
        int s = src[e];
        unsigned char st = state[e];
        unsigned idx = atomicAdd(&cnt[d], 1u);
        if (idx < CAP) bucket[d * CAP + idx] = (unsigned)s | (st ? 0x80000000u : 0u);
        int g = batch[s];
        meta[e] = (unsigned short)(g | (st ? 0 : 0x8000));
        return;
    }
    if (blockIdx.x >= 1624) {
        // ---- f32 transposed weights for the exact-refine arbiter ----
        int t2 = (blockIdx.x - 1624) * 256 + threadIdx.x;   // 0..61439
        if (t2 < 16384)      Wt[t2]         = W1[(t2 % 64) * 256 + t2 / 64];                 // W1t [256][64]
        else if (t2 < 49152) { int t = t2 - 16384; Wt[t2] = W2[(t % 256) * 128 + t / 256]; } // W2t [128][256]
        else if (t2 < 57344) { int t = t2 - 49152; Wt[t2] = W3[(t % 128) * 64 + t / 128]; }  // W3t [64][128]
        else                 { int t = t2 - 57344; Wt[t2] = P1[(t % 64) * 64 + t / 64]; }    // P1t [64][64]
        return;
    }
    // ---- weight prep: split f32 -> (Wh, Wl) f16, fragment-ordered (lo plane kept for layout compat) ----
    int tid = (blockIdx.x - 1563) * 256 + threadIdx.x;
    if (tid >= 15616) return;
    const float* W; int K, NT, Nreal, base, i;
    if (tid < 4096)       { W = W1; K = 64;  NT = 16; Nreal = 256; base = 0;      i = tid; }
    else if (tid < 12288) { W = W2; K = 256; NT = 8;  Nreal = 128; base = 65536;  i = tid - 4096; }
    else if (tid < 14336) { W = W3; K = 128; NT = 4;  Nreal = 64;  base = 196608; i = tid - 12288; }
    else if (tid < 15360) { W = P1; K = 64;  NT = 4;  Nreal = 64;  base = 229376; i = tid - 14336; }
    else                  { W = P2; K = 64;  NT = 1;  Nreal = 10;  base = 245760; i = tid - 15360; }
    int KB = K / 32;
    int lane = i & 63; int i2 = i >> 6;
    int nt = i2 % NT; int i3 = i2 / NT;
    int kb = i3 % KB; int ps = i3 / KB;
    unsigned short s[8];
    #pragma unroll
    for (int j = 0; j < 8; ++j) {
        int k = kb * 32 + ((lane >> 4) << 3) + j;
        int n = nt * 16 + (lane & 15);
        float wv = (n < Nreal) ? W[k * Nreal + n] : 0.f;
        unsigned short h = f2h_bits(wv);
        s[j] = ps ? f2h_bits(wv - h2f(h)) : h;
    }
    uint4 u;
    u.x = (unsigned)s[0] | ((unsigned)s[1] << 16);
    u.y = (unsigned)s[2] | ((unsigned)s[3] << 16);
    u.z = (unsigned)s[4] | ((unsigned)s[5] << 16);
    u.w = (unsigned)s[6] | ((unsigned)s[7] << 16);
    int frag = (ps * KB + kb) * NT + nt;
    *reinterpret_cast<uint4*>(Bpp + base + frag * 1024 + lane * 16) = u;
}

// ---------- 2) fused gather-aggregate + node reps (chunked gathers, same FP order) ----------
__global__ void k_aggrep(const float* __restrict__ x, const unsigned* __restrict__ cnt,
                         const unsigned* __restrict__ bucket, const float* __restrict__ Wg,
                         const float* __restrict__ bg, float* __restrict__ reps)
{
    __shared__ float sv[4][128];
    const int w = threadIdx.x >> 6, j = threadIdx.x & 63;
    const int n = blockIdx.x * 4 + w;
    unsigned c = cnt[n]; if (c > CAP) c = CAP;
    float sf = 0.f, so = 0.f;
    unsigned i = 0;
    for (; i + 4 <= c; i += 4) {
        unsigned p0 = bucket[n * CAP + i];
        unsigned p1 = bucket[n * CAP + i + 1];
        unsigned p2 = bucket[n * CAP + i + 2];
        unsigned p3 = bucket[n * CAP + i + 3];
        float v0 = x[(p0 & 0x7FFFFFFFu) * 64 + j];
        float v1 = x[(p1 & 0x7FFFFFFFu) * 64 + j];
        float v2 = x[(p2 & 0x7FFFFFFFu) * 64 + j];
        float v3 = x[(p3 & 0x7FFFFFFFu) * 64 + j];
        sf += v0; if (p0 & 0x80000000u) so += v0;
        sf += v1; if (p1 & 0x80000000u) so += v1;
        sf += v2; if (p2 & 0x80000000u) so += v2;
        sf += v3; if (p3 & 0x80000000u) so += v3;
    }
    for (; i < c; ++i) {
        unsigned p = bucket[n * CAP + i];
        float v = x[(p & 0x7FFFFFFFu) * 64 + j];
        sf += v;
        if (p & 0x80000000u) so += v;
    }
    float xv = x[n * 64 + j];
    sv[w][j]      = xv + sf;
    sv[w][64 + j] = xv + so;
    __syncthreads();
    const int o = j & 31;
    const float* svp = sv[w] + ((j >> 5) ? 64 : 0);
    float acc = 0.f;
    #pragma unroll 16
    for (int i2 = 0; i2 < 64; ++i2) acc += svp[i2] * Wg[i2 * 32 + o];
    float val = elu_fast(acc + bg[o]);
    float other = __shfl_xor(val, 32, 64);
    if (j < 32) reps[n * 32 + o] = val - other;
}

// ---------- 3) fused MFMA MLP: 64 edges/block, f16 hi-only acts, B-preload pipelining ----------
// LDS rotation: region A 16 KB @0, region B 32 KB @16384 -> 48 KB -> 3 blocks/CU.
#define OFF_A 0
#define OFF_B 16384
#define SM_BYTES 49152

template<int K, int N, int ACT>   // ACT: 0 linear, 1 elu, 2 logits f32 store
__device__ __forceinline__ void run_layer(char* sm, const char* gB, int inOff, int outOff,
                                          const float* __restrict__ bias, int w, int lane)
{
    constexpr int KB  = K / 32;
    constexpr int NT  = N / 16;
    constexpr int NTC = (NT < 8) ? NT : 8;
    constexpr int NH  = NT / NTC;
    constexpr int NTW = (NTC >= 4) ? (NTC / 4) : 1;

    __syncthreads();

    const int row0 = lane & 15;
    const int hi16 = (lane >> 4) * 16;   // byte offset of k-subgroup

    #pragma unroll
    for (int nh = 0; nh < NH; ++nh) {
        // ---- preload ALL B fragments for this nh (breaks the serialized L2 chain) ----
        f16x8 Bf[KB][NTW];
        #pragma unroll
        for (int kb = 0; kb < KB; ++kb) {
            #pragma unroll
            for (int q = 0; q < NTW; ++q) {
                int nt = (w * NTW + q) % NTC;
                Bf[kb][q] = *reinterpret_cast<const f16x8*>(
                    gB + ((kb * NT + nh * NTC + nt) * 1024) + lane * 16);
            }
        }

        f32x4 C[4][NTW];
        #pragma unroll
        for (int q = 0; q < NTW; ++q) {
            int nt = (w * NTW + q) % NTC;
            int n  = nh * NTC * 16 + nt * 16 + row0;
            float b = (ACT == 2) ? (n < 10 ? bias[n] : 0.f) : bias[n];
            #pragma unroll
            for (int mt = 0; mt < 4; ++mt) C[mt][q] = (f32x4){b, b, b, b};
        }

        #pragma unroll
        for (int kb = 0; kb < KB; ++kb) {
            f16x8 Ah[4];
            #pragma unroll
            for (int mt = 0; mt < 4; ++mt) {
                int row = mt * 16 + row0;
                int off = (((row * K + kb * 32) * 2) + hi16) ^ ((row & 7) << 4);
                Ah[mt] = *reinterpret_cast<const f16x8*>(sm + inOff + off);
            }
            #pragma unroll
            for (int q = 0; q < NTW; ++q) {
                #pragma unroll
                for (int mt = 0; mt < 4; ++mt)
                    C[mt][q] = __builtin_amdgcn_mfma_f32_16x16x32_f16(Ah[mt], Bf[kb][q], C[mt][q], 0, 0, 0);
            }
        }

        // epilogue (hi-only f16 store, or f32 for logits)
        #pragma unroll
        for (int q = 0; q < NTW; ++q) {
            int nt = (w * NTW + q) % NTC;
            int n  = nh * NTC * 16 + nt * 16 + row0;
            #pragma unroll
            for (int mt = 0; mt < 4; ++mt) {
                #pragma unroll
                for (int r = 0; r < 4; ++r) {
                    int row = mt * 16 + (lane >> 4) * 4 + r;
                    float v = C[mt][q][r];
                    if (ACT == 1) v = elu_fast(v);
                    if (ACT == 2) {
                        *reinterpret_cast<float*>(sm + outOff + (row * 16 + n) * 4) = v;
                    } else {
                        int off = ((row * N + n) * 2) ^ ((row & 7) << 4);
                        *reinterpret_cast<unsigned short*>(sm + outOff + off) = f2h_bits(v);
                    }
                }
            }
        }
    }
}

__global__ __launch_bounds__(256, 3) void k_mlp(
    const float* __restrict__ reps, const int* __restrict__ src, const int* __restrict__ dst,
    const unsigned short* __restrict__ meta, const int* __restrict__ y,
    const float* __restrict__ b1, const float* __restrict__ b2, const float* __restrict__ b3,
    const float* __restrict__ pb1, const float* __restrict__ pb2,
    const char* __restrict__ Bpp, float* __restrict__ lg_out, unsigned* __restrict__ m_u)
{
    __shared__ char sm[SM_BYTES];
    __shared__ int sSrc[64], sDst[64], sG[64], sCol[64], sAvail[64];
    const int t = threadIdx.x, w = t >> 6, lane = t & 63;
    const int ebase = blockIdx.x * 64;

    if (t < 64) {
        int e = ebase + t;
        sSrc[t] = src[e]; sDst[t] = dst[e];
        unsigned m = meta[e];
        int g = m & 0x1ff;
        sG[t] = g; sCol[t] = y[g];
        sAvail[t] = (m >> 15) & 1;
    }
    __syncthreads();

    // stage input tile: concat(reps[src], reps[dst]) -> f16, swizzled -> region A
    {
        int e = t >> 2, f0 = (t & 3) * 16;
        const float* rp = (f0 < 32) ? (reps + sSrc[e] * 32 + f0) : (reps + sDst[e] * 32 + (f0 - 32));
        float4 v0 = *reinterpret_cast<const float4*>(rp);
        float4 v1 = *reinterpret_cast<const float4*>(rp + 4);
        float4 v2 = *reinterpret_cast<const float4*>(rp + 8);
        float4 v3 = *reinterpret_cast<const float4*>(rp + 12);
        float vv[16] = {v0.x,v0.y,v0.z,v0.w, v1.x,v1.y,v1.z,v1.w,
                        v2.x,v2.y,v2.z,v2.w, v3.x,v3.y,v3.z,v3.w};
        unsigned pk[8];
        #pragma unroll
        for (int i = 0; i < 8; ++i)
            pk[i] = (unsigned)f2h_bits(vv[2*i]) | ((unsigned)f2h_bits(vv[2*i+1]) << 16);
        int b0 = (e * 64 + f0) * 2;
        uint4 u0 = {pk[0], pk[1], pk[2], pk[3]};
        uint4 u1 = {pk[4], pk[5], pk[6], pk[7]};
        *reinterpret_cast<uint4*>(sm + OFF_A + (b0 ^ ((e & 7) << 4)))        = u0;
        *reinterpret_cast<uint4*>(sm + OFF_A + ((b0 + 16) ^ ((e & 7) << 4))) = u1;
    }

    run_layer< 64, 256, 1>(sm, Bpp + 0,      OFF_A, OFF_B, b1,  w, lane);
    run_layer<256, 128, 1>(sm, Bpp + 65536,  OFF_B, OFF_A, b2,  w, lane);
    run_layer<128,  64, 0>(sm, Bpp + 196608, OFF_A, OFF_B, b3,  w, lane);
    run_layer< 64,  64, 1>(sm, Bpp + 229376, OFF_B, OFF_A, pb1, w, lane);
    run_layer< 64,  16, 2>(sm, Bpp + 245760, OFF_A, OFF_B, pb2, w, lane);
    __syncthreads();

    if (t < 64) {
        int col = sCol[t];
        float lg = *reinterpret_cast<const float*>(sm + OFF_B + (t * 16 + col) * 4);
        lg_out[ebase + t] = lg;
        float lgm = sAvail[t] ? lg : -INFINITY;
        atomicMax(&m_u[sG[t]], enc_f(lgm));
    }
}

// ---------- 4) exp + LDS-bucketed denom + candidate select ----------
__global__ void k_ex(const float* __restrict__ lg, const unsigned short* __restrict__ meta,
                     const unsigned* __restrict__ m_u, float* __restrict__ ex,
                     float* __restrict__ denom, unsigned* __restrict__ cand,
                     unsigned* __restrict__ ccnt)
{
    __shared__ float sden[N_GRAPHS];
    for (int i = threadIdx.x; i < N_GRAPHS; i += 256) sden[i] = 0.f;
    __syncthreads();
    for (int e = blockIdx.x * 256 + threadIdx.x; e < N_EDGES; e += gridDim.x * 256) {
        unsigned mt_ = meta[e];
        int g = mt_ & 0x1ff;
        float v = 0.f;
        if (mt_ & 0x8000) {
            float l = lg[e];
            float m = dec_f(m_u[g]);
            v = __expf(l - m);
            if (l >= m - DELTA) {
                unsigned i = atomicAdd(ccnt, 1u);
                if (i < CAND_MAX) cand[i] = (unsigned)e;
            }
        }
        ex[e] = v;
        atomicAdd(&sden[g], v);
    }
    __syncthreads();
    for (int i = threadIdx.x; i < N_GRAPHS; i += 256)
        if (sden[i] != 0.f) atomicAdd(&denom[i], sden[i]);
}

// ---------- 5) probs prologue + exact f32 recompute for ALL candidates + u64-key argmax ----------
__global__ __launch_bounds__(256) void k_refine(
    const float* __restrict__ reps, const int* __restrict__ src, const int* __restrict__ dst,
    const unsigned short* __restrict__ meta, const int* __restrict__ y,
    const float* __restrict__ Wt,
    const float* __restrict__ b1, const float* __restrict__ b2, const float* __restrict__ b3,
    const float* __restrict__ pb1, const float* __restrict__ P2, const float* __restrict__ pb2,
    const float* __restrict__ ex, const float* __restrict__ denom, float* __restrict__ out,
    const unsigned* __restrict__ cand, const unsigned* __restrict__ ccnt,
    unsigned long long* __restrict__ key)
{
    // --- probs: grid-stride over all edges ---
    for (int e = blockIdx.x * 256 + threadIdx.x; e < N_EDGES; e += gridDim.x * 256)
        out[e] = ex[e] / denom[meta[e] & 0x1ff];

    __shared__ float sa[4][256], sb[4][256];
    const int t = threadIdx.x, w = t >> 6, lane = t & 63;
    const float* W1t = Wt;            // [256][64]
    const float* W2t = Wt + 16384;    // [128][256]
    const float* W3t = Wt + 49152;    // [64][128]
    const float* P1t = Wt + 57344;    // [64][64]
    unsigned cnt = *ccnt; if (cnt > CAND_MAX) cnt = CAND_MAX;
    for (unsigned base = blockIdx.x * 4; base < cnt; base += gridDim.x * 4) {
        unsigned ci = base + w;
        bool act = ci < cnt;
        int g = 0, col = 0; unsigned e = 0;
        if (act) {
            e = cand[ci];
            int s_ = src[e], d_ = dst[e];
            g = meta[e] & 0x1ff; col = y[g];
            sa[w][lane] = (lane < 32) ? reps[s_ * 32 + lane] : reps[d_ * 32 + (lane - 32)];
        }
        __syncthreads();
        // L1: 64 -> 256
        {
            float acc[4];
            #pragma unroll
            for (int r = 0; r < 4; ++r) acc[r] = b1[lane + 64 * r];
            #pragma unroll
            for (int k = 0; k < 64; k += 4) {
                float4 a = *reinterpret_cast<const float4*>(&sa[w][k]);
                #pragma unroll
                for (int r = 0; r < 4; ++r) {
                    float4 wv = *reinterpret_cast<const float4*>(&W1t[(lane + 64 * r) * 64 + k]);
                    acc[r] += a.x * wv.x + a.y * wv.y + a.z * wv.z + a.w * wv.w;
                }
            }
            #pragma unroll
            for (int r = 0; r < 4; ++r) sb[w][lane + 64 * r] = elu_f(acc[r]);
        }
        __syncthreads();
        // L2: 256 -> 128
        {
            float acc0 = b2[lane], acc1 = b2[lane + 64];
            #pragma unroll
            for (int k = 0; k < 256; k += 4) {
                float4 a = *reinterpret_cast<const float4*>(&sb[w][k]);
                float4 w0 = *reinterpret_cast<const float4*>(&W2t[lane * 256 + k]);
                float4 w1 = *reinterpret_cast<const float4*>(&W2t[(lane + 64) * 256 + k]);
                acc0 += a.x * w0.x + a.y * w0.y + a.z * w0.z + a.w * w0.w;
                acc1 += a.x * w1.x + a.y * w1.y + a.z * w1.z + a.w * w1.w;
            }
            sa[w][lane] = elu_f(acc0); sa[w][lane + 64] = elu_f(acc1);
        }
        __syncthreads();
        // L3: 128 -> 64 (no act)
        {
            float acc = b3[lane];
            #pragma unroll
            for (int k = 0; k < 128; k += 4) {
                float4 a = *reinterpret_cast<const float4*>(&sa[w][k]);
                float4 wv = *reinterpret_cast<const float4*>(&W3t[lane * 128 + k]);
                acc += a.x * wv.x + a.y * wv.y + a.z * wv.z + a.w * wv.w;
            }
            sb[w][lane] = acc;
        }
        __syncthreads();
        // P1: 64 -> 64 + elu, then P2 col dot
        float p1o;
        {
            float acc = pb1[lane];
            #pragma unroll
            for (int k = 0; k < 64; k += 4) {
                float4 a = *reinterpret_cast<const float4*>(&sb[w][k]);
                float4 wv = *reinterpret_cast<const float4*>(&P1t[lane * 64 + k]);
                acc += a.x * wv.x + a.y * wv.y + a.z * wv.z + a.w * wv.w;
            }
            p1o = elu_f(acc);
        }
        float part = act ? p1o * P2[lane * 10 + col] : 0.f;
        #pragma unroll
        for (int m = 32; m > 0; m >>= 1) part += __shfl_xor(part, m, 64);
        if (act && lane == 0) {
            float lgf = part + pb2[col];
            unsigned long long k64 = ((unsigned long long)enc_f(lgf) << 32) | (unsigned)(~e);
            atomicMax(&key[g], k64);
        }
        __syncthreads();
    }
}

// ---------- 6) finalize ----------
__global__ void k_final(const float* __restrict__ denom, const unsigned long long* __restrict__ key,
                        float* __restrict__ out)
{
    int g = blockIdx.x * 256 + threadIdx.x;
    if (g >= N_GRAPHS) return;
    out[N_EDGES + g] = 1.0f / denom[g];
    unsigned long long k = key[g];
    out[N_EDGES + N_GRAPHS + g] = (float)(~(unsigned)(k & 0xFFFFFFFFull));
}

// ---------- launch ----------
extern "C" void kernel_launch(void* const* d_in, const int* in_sizes, int n_in,
                              void* d_out, int out_size, void* d_ws, size_t ws_size,
                              hipStream_t stream)
{
    const float* x   = (const float*)d_in[0];
    const int*   ei  = (const int*)d_in[1];
    const int*   src = ei;
    const int*   dst = ei + N_EDGES;
    const unsigned char* state = (const unsigned char*)d_in[2];
    const int*   batch = (const int*)d_in[3];
    const int*   y     = (const int*)d_in[4];
    const float* Wg = (const float*)d_in[5];
    const float* bg = (const float*)d_in[6];
    const float* W1 = (const float*)d_in[7];
    const float* b1 = (const float*)d_in[8];
    const float* W2 = (const float*)d_in[9];
    const float* b2 = (const float*)d_in[10];
    const float* W3 = (const float*)d_in[11];
    const float* b3 = (const float*)d_in[12];
    const float* P1 = (const float*)d_in[13];
    const float* pb1= (const float*)d_in[14];
    const float* P2 = (const float*)d_in[15];
    const float* pb2= (const float*)d_in[16];

    float* ws = (float*)d_ws;
    unsigned*           bucket = (unsigned*)ws;                       // 3,200,000 u32
    unsigned*           cnt    = (unsigned*)(ws + 3200000);           //    50,000 u32
    unsigned*           m_u    = (unsigned*)(ws + 3250000);           // 500
    float*              denom  = (float*)(ws + 3250500);              // 500
    unsigned*           ccnt   = (unsigned*)(ws + 3251000);           // 1 (+1 pad)
    unsigned long long* key    = (unsigned long long*)(ws + 3251002); // 500 u64 (8B-aligned)
    float*              reps   = ws + 3252004;                        // 1,600,000 f32
    float*              lg     = ws + 4852004;                        //   400,000 f32
    float*              ex     = ws + 5252004;                        //   400,000 f32
    unsigned short*     meta   = (unsigned short*)(ws + 5652004);     //   400,000 u16
    char*               Bpp    = (char*)(ws + 5852004);               // 249,856 B (16B-aligned)
    unsigned*           cand   = (unsigned*)(ws + 5914468);           // 262,144 u32
    float*              Wt     = ws + 6176612;                        //  61,440 f32 (16B-aligned)

    // single zero memset: cnt + m_u + denom + ccnt + pad + key (contiguous)
    hipMemsetAsync(cnt, 0, (size_t)(3252002 - 3200000) * 4, stream);

    k_place  <<<1864, 256, 0, stream>>>(src, dst, state, batch, cnt, bucket, meta,
                                        W1, W2, W3, P1, P2, Bpp, Wt);
    k_aggrep <<<N_NODES / 4, 256, 0, stream>>>(x, cnt, bucket, Wg, bg, reps);
    k_mlp    <<<N_EDGES / 64, 256, 0, stream>>>(reps, src, dst, meta, y,
                                                b1, b2, b3, pb1, pb2, Bpp, lg, m_u);
    k_ex     <<<256, 256, 0, stream>>>(lg, meta, m_u, ex, denom, cand, ccnt);
    k_refine <<<2048, 256, 0, stream>>>(reps, src, dst, meta, y, Wt,
                                        b1, b2, b3, pb1, P2, pb2,
                                        ex, denom, (float*)d_out,
                                        cand, ccnt, key);
    k_final  <<<2, 256, 0, stream>>>(denom, key, (float*)d_out);
}